// Round 1
// baseline (2063.210 us; speedup 1.0000x reference)
//
#include <hip/hip_runtime.h>
#include <hip/hip_bf16.h>

// Problem constants (fixed by setup_inputs)
#define B_    4
#define S_    512
#define R_    2048      // B*S rows
#define V_    32000     // vocab
#define D_    256       // emb dim
#define NIT_  3
#define TB_   640       // threads per row-block (10 waves)
#define EJ_   25        // float2 chunks per thread: 640*25*2 = 32000
#define NW_   (TB_/64)  // waves per block = 10

typedef __attribute__((ext_vector_type(8))) short bh8;
typedef __attribute__((ext_vector_type(4))) float f32x4;

__device__ __forceinline__ unsigned short f2bf(float x) {
  unsigned int u = __float_as_uint(x);
  unsigned int lsb = (u >> 16) & 1u;
  u += 0x7fffu + lsb;                 // round-to-nearest-even
  return (unsigned short)(u >> 16);
}

__device__ __forceinline__ float wredMax(float v) {
#pragma unroll
  for (int m = 32; m; m >>= 1) v = fmaxf(v, __shfl_xor(v, m, 64));
  return v;
}
__device__ __forceinline__ float wredSum(float v) {
#pragma unroll
  for (int m = 32; m; m >>= 1) v += __shfl_xor(v, m, 64);
  return v;
}

__device__ __forceinline__ float bredMax(float v, float* sh) {
  const int w = threadIdx.x >> 6, ln = threadIdx.x & 63;
  v = wredMax(v);
  if (ln == 0) sh[w] = v;
  __syncthreads();
  float r = (ln < NW_) ? sh[ln] : -3.0e38f;
  r = wredMax(r);
  __syncthreads();
  return r;
}
__device__ __forceinline__ float bredSum(float v, float* sh) {
  const int w = threadIdx.x >> 6, ln = threadIdx.x & 63;
  v = wredSum(v);
  if (ln == 0) sh[w] = v;
  __syncthreads();
  float r = (ln < NW_) ? sh[ln] : 0.f;
  r = wredSum(r);
  __syncthreads();
  return r;
}

// argmax with first-occurrence (lowest index) tie-break, carrying the logit at the max
__device__ __forceinline__ void bredArgmax(float& val, int& idx, float& aux,
                                           float* shf, int* shi, float* sha) {
#pragma unroll
  for (int m = 32; m; m >>= 1) {
    float ov = __shfl_xor(val, m, 64);
    int   oi = __shfl_xor(idx, m, 64);
    float oa = __shfl_xor(aux, m, 64);
    if (ov > val || (ov == val && oi < idx)) { val = ov; idx = oi; aux = oa; }
  }
  const int w = threadIdx.x >> 6, ln = threadIdx.x & 63;
  if (ln == 0) { shf[w] = val; shi[w] = idx; sha[w] = aux; }
  __syncthreads();
  if (ln < NW_) { val = shf[ln]; idx = shi[ln]; aux = sha[ln]; }
  else          { val = -3.0e38f; idx = 0x7fffffff; aux = 0.f; }
#pragma unroll
  for (int m = 32; m; m >>= 1) {
    float ov = __shfl_xor(val, m, 64);
    int   oi = __shfl_xor(idx, m, 64);
    float oa = __shfl_xor(aux, m, 64);
    if (ov > val || (ov == val && oi < idx)) { val = ov; idx = oi; aux = oa; }
  }
  __syncthreads();
}

// ---------------- kernel A: pack emb fp32 [V][D] -> bf16 frag-blocks ----------------
// frag-block (nt, kcb) covers n in [16nt,16nt+16), k in [32kcb, 32kcb+32); 1 KiB each,
// laid out so a B-frag load is lane-contiguous 16 B: lane = (n&15) | (((k>>3)&3)<<4),
// within lane: 8 consecutive k (bf16).
__global__ __launch_bounds__(256) void pack_emb(const float* __restrict__ emb,
                                                bh8* __restrict__ packed) {
  const int gid = blockIdx.x * 256 + threadIdx.x;  // 0 .. 4000*256-1
  const int n  = gid & 255;
  const int kg = gid >> 8;      // 0..3999
  const int k0 = kg * 8;
  bh8 out;
#pragma unroll
  for (int i = 0; i < 8; ++i) {
    float f = emb[(size_t)(k0 + i) * D_ + n];
    out[i] = (short)f2bf(f);
  }
  const int nt   = n >> 4;
  const int kcb  = k0 >> 5;
  const int lane = (n & 15) | (((k0 >> 3) & 3) << 4);
  packed[(size_t)(nt * 1000 + kcb) * 64 + lane] = out;
}

// ---------------- kernel B: per-row fused pipeline ----------------
__global__ __launch_bounds__(TB_) void rowwise(
    const float* __restrict__ logits, const float* __restrict__ emb,
    const float* __restrict__ u_g1, const float* __restrict__ u_t0,
    const float* __restrict__ u_other, const float* __restrict__ u_target,
    float* __restrict__ out_f, float* __restrict__ out_p1, float* __restrict__ out_hard,
    unsigned int* __restrict__ p2_out, int* __restrict__ idx_out, int write_hard)
{
  __shared__ float shf[NW_];
  __shared__ int   shi[NW_];
  __shared__ float sha[NW_];
  const int r = blockIdx.x, t = threadIdx.x;

  const float2* lg2 = (const float2*)(logits + (size_t)r * V_);
  const float2* ug2 = (const float2*)(u_g1   + (size_t)r * V_);

  float lg[2 * EJ_];   // logits, resident all phases
  float tm[2 * EJ_];   // z1 -> exp(z1-M1) -> g_o -> s -> exp(s-M2)

  // ---- phase 1: gumbel-1, max/argmax ----
  float bv = -3.0e38f; int bidx = 0; float blg = 0.f;
#pragma unroll
  for (int j = 0; j < EJ_; ++j) {
    const int c = t + j * TB_;
    const float2 L = lg2[c];
    const float2 U = ug2[c];
    const float g0 = fminf(-__logf(-__logf(U.x)), 1e10f);
    const float g1 = fminf(-__logf(-__logf(U.y)), 1e10f);
    const float z0 = L.x + g0, z1 = L.y + g1;
    lg[2 * j] = L.x; lg[2 * j + 1] = L.y;
    tm[2 * j] = z0;  tm[2 * j + 1] = z1;
    if (z0 > bv) { bv = z0; bidx = 2 * c;     blg = L.x; }
    if (z1 > bv) { bv = z1; bidx = 2 * c + 1; blg = L.y; }
  }
  float mval = bv; int idx = bidx; float tl = blg;
  bredArgmax(mval, idx, tl, shf, shi, sha);
  const float M1 = mval;

  // ---- p1 = softmax(z1) ----
  float s1 = 0.f;
#pragma unroll
  for (int k = 0; k < 2 * EJ_; ++k) { const float e = __expf(tm[k] - M1); tm[k] = e; s1 += e; }
  const float Z1 = bredSum(s1, shf);
  const float inv1 = 1.0f / Z1;

  float2* p1row = (float2*)(out_p1 + (size_t)r * V_);
#pragma unroll
  for (int j = 0; j < EJ_; ++j) {
    const int c = t + j * TB_;
    p1row[c] = make_float2(tm[2 * j] * inv1, tm[2 * j + 1] * inv1);
  }
  if (write_hard) {
    float2* hrow = (float2*)(out_hard + (size_t)r * V_);
#pragma unroll
    for (int j = 0; j < EJ_; ++j) {
      const int c = t + j * TB_;
      hrow[c] = make_float2((2 * c) == idx ? 1.f : 0.f, (2 * c + 1) == idx ? 1.f : 0.f);
    }
  }
  if (t < D_) out_f[(size_t)r * D_ + t] = emb[(size_t)idx * D_ + t];
  if (t == 0) idx_out[r] = idx;

  // ---- conditional-Gumbel rescan loop ----
  float gt = fminf(-__logf(-__logf(u_t0[r])), 1e10f);
#pragma unroll
  for (int i = 0; i < NIT_; ++i) {
    const float2* uo2 = (const float2*)(u_other + ((size_t)i * R_ + r) * V_);
    float lmax = -3.0e38f;
#pragma unroll
    for (int j = 0; j < EJ_; ++j) {
      const int c = t + j * TB_;
      const float2 U = uo2[c];
      {
        const int k = 2 * j, v = 2 * c;
        const float a = gt + tl - lg[k];
        const float upper = __expf(-__expf(-a));
        const float go = -__logf(-__logf(U.x * upper + 1e-20f) + 1e-20f);
        if (i == NIT_ - 1) tm[k] = go;
        const float cand = (v == idx) ? -1e9f : (go + lg[k] - tl);
        lmax = fmaxf(lmax, cand);
      }
      {
        const int k = 2 * j + 1, v = 2 * c + 1;
        const float a = gt + tl - lg[k];
        const float upper = __expf(-__expf(-a));
        const float go = -__logf(-__logf(U.y * upper + 1e-20f) + 1e-20f);
        if (i == NIT_ - 1) tm[k] = go;
        const float cand = (v == idx) ? -1e9f : (go + lg[k] - tl);
        lmax = fmaxf(lmax, cand);
      }
    }
    const float lraw = bredMax(lmax, shf);
    const float lower = __expf(-__expf(-lraw));
    const float ut = u_target[(size_t)i * R_ + r];
    gt = -__logf(-__logf(ut * (1.f - lower) + lower + 1e-20f) + 1e-20f);
  }

  // ---- p2 = softmax(logits + noise2), noise2 = g_o except g_target at idx ----
  float m2 = -3.0e38f;
#pragma unroll
  for (int j = 0; j < EJ_; ++j) {
    const int c = t + j * TB_;
    {
      const int k = 2 * j, v = 2 * c;
      const float sv = (v == idx) ? (tl + gt) : (lg[k] + tm[k]);
      tm[k] = sv; m2 = fmaxf(m2, sv);
    }
    {
      const int k = 2 * j + 1, v = 2 * c + 1;
      const float sv = (v == idx) ? (tl + gt) : (lg[k] + tm[k]);
      tm[k] = sv; m2 = fmaxf(m2, sv);
    }
  }
  const float M2 = bredMax(m2, shf);
  float s2 = 0.f;
#pragma unroll
  for (int k = 0; k < 2 * EJ_; ++k) { const float e = __expf(tm[k] - M2); tm[k] = e; s2 += e; }
  const float Z2 = bredSum(s2, shf);
  const float inv2 = 1.0f / Z2;

  unsigned int* p2row = p2_out + (size_t)r * (V_ / 2);
#pragma unroll
  for (int j = 0; j < EJ_; ++j) {
    const int c = t + j * TB_;
    const unsigned int u0 = f2bf(tm[2 * j] * inv2);
    const unsigned int u1 = f2bf(tm[2 * j + 1] * inv2);
    p2row[c] = u0 | (u1 << 16);
  }
}

// ---------------- kernel C: g = p2 @ emb via bf16 MFMA, K-split + atomics ----------------
#define MT_ 128
#define KS_ 20
#define KC_ (V_ / KS_)   // 1600 = 50 * BK(32)

__global__ __launch_bounds__(512) void gemm_p2_emb(
    const unsigned short* __restrict__ p2,   // bf16 [R_][V_]
    const bh8* __restrict__ embp,            // packed frag-blocks
    float* __restrict__ g)                   // [R_][D_], pre-zeroed
{
  const int w = threadIdx.x >> 6, ln = threadIdx.x & 63;
  const int row0 = blockIdx.x * MT_ + w * 16;
  const int kbase = blockIdx.y * KC_;
  const int rowA = row0 + (ln & 15);
  const int koff = (ln >> 4) * 8;

  f32x4 acc[16];
#pragma unroll
  for (int i = 0; i < 16; ++i) acc[i] = (f32x4){0.f, 0.f, 0.f, 0.f};

  const bh8* aBase = (const bh8*)(p2 + (size_t)rowA * V_);
  for (int kc = kbase; kc < kbase + KC_; kc += 32) {
    const bh8 afrag = aBase[(kc + koff) >> 3];
#pragma unroll
    for (int nt = 0; nt < 16; ++nt) {
      const bh8 bfrag = embp[(size_t)(nt * 1000 + (kc >> 5)) * 64 + ln];
      acc[nt] = __builtin_amdgcn_mfma_f32_16x16x32_bf16(afrag, bfrag, acc[nt], 0, 0, 0);
    }
  }
  const int orow = row0 + (ln >> 4) * 4;
  const int ocol = ln & 15;
#pragma unroll
  for (int nt = 0; nt < 16; ++nt) {
#pragma unroll
    for (int i = 0; i < 4; ++i)
      atomicAdd(&g[(size_t)(orow + i) * D_ + nt * 16 + ocol], acc[nt][i]);
  }
}

// ---------------- kernel D (fallback only): rebuild one-hot hard output ----------------
__global__ __launch_bounds__(256) void rewrite_hard(float* __restrict__ hard,
                                                    const int* __restrict__ idxs) {
  const int r = blockIdx.x;
  const int idx = idxs[r];
  float4* row = (float4*)(hard + (size_t)r * V_);
  for (int j = threadIdx.x; j < V_ / 4; j += 256) {
    float4 z = {0.f, 0.f, 0.f, 0.f};
    if ((idx >> 2) == j) ((float*)&z)[idx & 3] = 1.f;
    row[j] = z;
  }
}

extern "C" void kernel_launch(void* const* d_in, const int* in_sizes, int n_in,
                              void* d_out, int out_size, void* d_ws, size_t ws_size,
                              hipStream_t stream) {
  const float* logits   = (const float*)d_in[0];
  const float* emb      = (const float*)d_in[1];
  // d_in[2..6] (sent_mask, f_mean, g_mean, g2_mean, fg_mean) are unused by the outputs
  const float* u_g1     = (const float*)d_in[7];
  const float* u_t0     = (const float*)d_in[8];
  const float* u_other  = (const float*)d_in[9];
  const float* u_target = (const float*)d_in[10];

  float* out      = (float*)d_out;
  float* out_f    = out;                       // 524288
  float* out_p1   = out + 524288;              // 65536000
  float* out_hard = out + 66060288;            // 65536000
  float* out_g    = out + 131596288;           // 524288

  char* ws = (char*)d_ws;
  bh8* embp   = (bh8*)ws;                      // 16,384,000 B packed emb bf16
  int* idxbuf = (int*)(ws + 16384000);         // 8,192 B row argmax
  const size_t p2_off = 16392192;              // 16-aligned
  const size_t need   = p2_off + (size_t)R_ * V_ * 2;  // + 131,072,000 B p2 bf16
  const bool primary = ws_size >= need;
  unsigned int* p2buf = primary ? (unsigned int*)(ws + p2_off)
                                : (unsigned int*)out_hard;  // stage p2 in hard slot

  pack_emb<<<4000, 256, 0, stream>>>(emb, embp);
  rowwise<<<R_, TB_, 0, stream>>>(logits, emb, u_g1, u_t0, u_other, u_target,
                                  out_f, out_p1, out_hard, p2buf, idxbuf,
                                  primary ? 1 : 0);
  hipMemsetAsync(out_g, 0, (size_t)R_ * D_ * sizeof(float), stream);
  gemm_p2_emb<<<dim3(R_ / MT_, KS_), 512, 0, stream>>>(
      (const unsigned short*)p2buf, embp, out_g);
  if (!primary)
    rewrite_hard<<<R_, 256, 0, stream>>>(out_hard, idxbuf);
}